// Round 5
// baseline (545.063 us; speedup 1.0000x reference)
//
#include <hip/hip_runtime.h>
#include <hip/hip_bf16.h>

#define B_SZ 64
#define T_SZ 2048
#define EPROJS 512
#define DUNITS 1024
#define ATT_DIM 320
#define NCH 10
#define KFILT 201
#define PAD 100

typedef __attribute__((ext_vector_type(8))) __bf16 bf16x8;
typedef __attribute__((ext_vector_type(4))) float f32x4;
typedef __attribute__((ext_vector_type(8))) unsigned short u16x8;

__device__ __forceinline__ unsigned short f2b(float f) {
    __bf16 h = (__bf16)f;
    return __builtin_bit_cast(unsigned short, h);
}

// ---------- W_enc f32 -> bf16 ----------
__global__ void cvt_wenc(const float* __restrict__ W, unsigned short* __restrict__ out) {
    int i = (blockIdx.x * 256 + threadIdx.x) * 4;
    float4 v = *(const float4*)(W + i);
    ushort4 o;
    o.x = f2b(v.x); o.y = f2b(v.y); o.z = f2b(v.z); o.w = f2b(v.w);
    *(ushort4*)(out + i) = o;
}

// ---------- dec_feat[b][a] = dec_z[b] . W_dec[a] + b_enc[a] ----------
__global__ void dec_feat_k(const float* __restrict__ dec_z, const float* __restrict__ W_dec,
                           const float* __restrict__ b_enc, float* __restrict__ df) {
    int b = blockIdx.x;
    int a = threadIdx.x;          // 320 threads
    const float4* z = (const float4*)(dec_z + b * DUNITS);
    const float4* w = (const float4*)(W_dec + (size_t)a * DUNITS);
    float s = b_enc[a];
    #pragma unroll 4
    for (int d = 0; d < DUNITS / 4; ++d) {
        float4 zv = z[d], wv = w[d];
        s += zv.x * wv.x + zv.y * wv.y + zv.z * wv.z + zv.w * wv.w;
    }
    df[b * ATT_DIM + a] = s;
}

// ---------- att_conv[b][c][t] ----------
__global__ void conv_k(const float* __restrict__ ap, const float* __restrict__ cw,
                       float* __restrict__ out) {
    int b = blockIdx.x, c = blockIdx.y;
    __shared__ float s_ap[T_SZ];
    __shared__ float s_cw[KFILT];
    int tid = threadIdx.x;
    for (int i = tid; i < T_SZ; i += 256) s_ap[i] = ap[b * T_SZ + i];
    for (int i = tid; i < KFILT; i += 256) s_cw[i] = cw[c * KFILT + i];
    __syncthreads();
    for (int j = 0; j < T_SZ / 256; ++j) {
        int t = tid + j * 256;
        int klo = max(0, PAD - t);
        int khi = min(KFILT, T_SZ + PAD - t);
        float s = 0.f;
        for (int k = klo; k < khi; ++k) s += s_ap[t - PAD + k] * s_cw[k];
        out[((size_t)(b * NCH + c)) * T_SZ + t] = s;
    }
}

// ---------- energy kernel: round-1 mechanics + BK=32 LDS double-buffer ----------
// LDS per chunk: granule-major [g in 0..3][wr in 0..319] of 16B granules;
// granule (g,wr) holds W[wr][k0 + g*8 .. +8]. Linear granule index i = g*320+wr.
__global__ __launch_bounds__(256, 2) void energy_k(
    const float* __restrict__ enc, const unsigned short* __restrict__ wbf,
    const float* __restrict__ df, const float* __restrict__ att_conv,
    const float* __restrict__ W_att, const float* __restrict__ W_g,
    float* __restrict__ e_out)
{
    __shared__ unsigned short sW[2][1280 * 8];    // 2 x 20 KB
    __shared__ float sConv[NCH * 64];             // 2.5 KB -> total 42.6 KB, 3 blocks/CU

    int tid = threadIdx.x;
    int lane = tid & 63, wave = tid >> 6;
    int blk = blockIdx.x;
    int b = blk >> 5;             // 32 tiles of 64 t's per b
    int t0 = (blk & 31) << 6;

    int m15 = lane & 15, kg = lane >> 4;
    int row = t0 + wave * 16 + m15;
    const float* aP = enc + ((size_t)b * T_SZ + row) * EPROJS;

    // per-thread staging coordinates: i = tid + j*256, j<5 (exactly 1280)
    // g = i/320 via (q*205)>>10 with q=i>>6 ; wr = i - g*320
    // prologue: stage chunk 0 into buffer 0
    #pragma unroll
    for (int j = 0; j < 5; ++j) {
        int i = tid + j * 256;
        int q = i >> 6;
        int g = (q * 205) >> 10;
        int wr = i - g * 320;
        u16x8 v = *(const u16x8*)(wbf + (size_t)wr * EPROJS + g * 8);
        *(u16x8*)(&sW[0][i * 8]) = v;
    }
    for (int i = tid; i < NCH * 64; i += 256)
        sConv[i] = att_conv[((size_t)(b * NCH + (i >> 6))) * T_SZ + t0 + (i & 63)];

    f32x4 acc[20];
    #pragma unroll
    for (int n = 0; n < 20; ++n) acc[n] = (f32x4){0.f, 0.f, 0.f, 0.f};

    __syncthreads();

    for (int t = 0; t < 16; ++t) {
        int cur = t & 1;
        if (t < 15) {
            // stage chunk t+1 into the other buffer (write-early: no regs live across compute)
            int k0n = (t + 1) * 32;
            #pragma unroll
            for (int j = 0; j < 5; ++j) {
                int i = tid + j * 256;
                int q = i >> 6;
                int g = (q * 205) >> 10;
                int wr = i - g * 320;
                u16x8 v = *(const u16x8*)(wbf + (size_t)wr * EPROJS + k0n + g * 8);
                *(u16x8*)(&sW[cur ^ 1][i * 8]) = v;
            }
        }

        // compute chunk t from buffer cur
        int k0 = t * 32;
        const float4 v0 = *(const float4*)(aP + k0 + kg * 8);
        const float4 v1 = *(const float4*)(aP + k0 + kg * 8 + 4);
        bf16x8 af;
        af[0] = (__bf16)v0.x; af[1] = (__bf16)v0.y; af[2] = (__bf16)v0.z; af[3] = (__bf16)v0.w;
        af[4] = (__bf16)v1.x; af[5] = (__bf16)v1.y; af[6] = (__bf16)v1.z; af[7] = (__bf16)v1.w;

        const unsigned short* sw = sW[cur];
        #pragma unroll
        for (int nt = 0; nt < 20; ++nt) {
            int wr = nt * 16 + m15;
            bf16x8 wf = *(const bf16x8*)(sw + (kg * 320 + wr) * 8);
            acc[nt] = __builtin_amdgcn_mfma_f32_16x16x32_bf16(af, wf, acc[nt], 0, 0, 0);
        }
        __syncthreads();
    }

    // epilogue: e[t] = sum_a Wg[a] * tanh(acc + df[a] + att_feat[t,a])
    int tl_base = wave * 16 + kg * 4;
    float s[4] = {0.f, 0.f, 0.f, 0.f};
    const float* dfb = df + b * ATT_DIM;
    #pragma unroll
    for (int nt = 0; nt < 20; ++nt) {
        int col = nt * 16 + m15;
        float wa[NCH];
        #pragma unroll
        for (int c = 0; c < NCH; ++c) wa[c] = W_att[col * NCH + c];   // L1-resident 12.8 KB
        float dfv = dfb[col], wg = W_g[col];
        #pragma unroll
        for (int r = 0; r < 4; ++r) {
            int tl = tl_base + r;
            float v = acc[nt][r] + dfv;
            #pragma unroll
            for (int c = 0; c < NCH; ++c) v += wa[c] * sConv[c * 64 + tl];
            v = fminf(fmaxf(v, -15.f), 15.f);
            float e2 = __expf(2.f * v);
            s[r] += wg * ((e2 - 1.f) / (e2 + 1.f));
        }
    }
    #pragma unroll
    for (int r = 0; r < 4; ++r) {
        float sv = s[r];
        sv += __shfl_xor(sv, 1); sv += __shfl_xor(sv, 2);
        sv += __shfl_xor(sv, 4); sv += __shfl_xor(sv, 8);
        if (m15 == 0) e_out[b * T_SZ + t0 + tl_base + r] = sv;
    }
}

// ---------- masked softmax over T, per b ----------
__global__ void softmax_k(const float* __restrict__ e, const int* __restrict__ len,
                          float* __restrict__ w_out, float* __restrict__ w_ws) {
    int b = blockIdx.x, tid = threadIdx.x;
    int lane = tid & 63, wave = tid >> 6;
    int L = len[b];
    float ev[8];
    float m = -1e30f;
    #pragma unroll
    for (int i = 0; i < 8; ++i) {
        int t = tid + i * 256;
        float x = e[b * T_SZ + t];
        if (t >= L) x = -1e30f;
        ev[i] = x;
        m = fmaxf(m, x);
    }
    #pragma unroll
    for (int o = 32; o > 0; o >>= 1) m = fmaxf(m, __shfl_xor(m, o));
    __shared__ float sred[4];
    if (lane == 0) sred[wave] = m;
    __syncthreads();
    m = fmaxf(fmaxf(sred[0], sred[1]), fmaxf(sred[2], sred[3]));

    float ex[8];
    float sum = 0.f;
    #pragma unroll
    for (int i = 0; i < 8; ++i) { ex[i] = __expf(2.f * (ev[i] - m)); sum += ex[i]; }
    #pragma unroll
    for (int o = 32; o > 0; o >>= 1) sum += __shfl_xor(sum, o);
    __shared__ float sred2[4];
    if (lane == 0) sred2[wave] = sum;
    __syncthreads();
    sum = sred2[0] + sred2[1] + sred2[2] + sred2[3];
    float inv = 1.f / sum;
    #pragma unroll
    for (int i = 0; i < 8; ++i) {
        int t = tid + i * 256;
        float w = ex[i] * inv;
        w_out[b * T_SZ + t] = w;
        w_ws[b * T_SZ + t] = w;
    }
}

// ---------- context partial: branchless, float4/lane ----------
__global__ void ctx_partial_k(const float* __restrict__ enc, const float* __restrict__ w,
                              float* __restrict__ part) {
    int b = blockIdx.x, tc = blockIdx.y, tid = threadIdx.x;
    int half = tid >> 7;          // 0/1: even/odd rows
    int c4 = tid & 127;           // float4 column index (128*4 = 512)
    f32x4 s = (f32x4){0.f, 0.f, 0.f, 0.f};
    int tb = tc * 128;
    #pragma unroll 4
    for (int i = half; i < 128; i += 2) {
        float wv = w[b * T_SZ + tb + i];              // masked rows have wv == 0 exactly
        f32x4 v = *(const f32x4*)(enc + ((size_t)b * T_SZ + tb + i) * EPROJS + c4 * 4);
        s += wv * v;
    }
    *(f32x4*)(part + ((size_t)(b * 32 + tc * 2 + half)) * EPROJS + c4 * 4) = s;
}

__global__ void ctx_reduce_k(const float* __restrict__ part, float* __restrict__ c_out) {
    int b = blockIdx.x;
    int c4 = threadIdx.x;         // 128 threads, float4 each
    f32x4 s = (f32x4){0.f, 0.f, 0.f, 0.f};
    #pragma unroll
    for (int tc = 0; tc < 32; ++tc)
        s += *(const f32x4*)(part + ((size_t)(b * 32 + tc)) * EPROJS + c4 * 4);
    *(f32x4*)(c_out + b * EPROJS + c4 * 4) = s;
}

extern "C" void kernel_launch(void* const* d_in, const int* in_sizes, int n_in,
                              void* d_out, int out_size, void* d_ws, size_t ws_size,
                              hipStream_t stream) {
    const float* enc      = (const float*)d_in[0];
    const int*   len      = (const int*)d_in[1];
    const float* dec_z    = (const float*)d_in[2];
    const float* att_prev = (const float*)d_in[3];
    const float* W_enc    = (const float*)d_in[4];
    const float* b_enc    = (const float*)d_in[5];
    const float* W_dec    = (const float*)d_in[6];
    const float* W_att    = (const float*)d_in[7];
    const float* conv_w   = (const float*)d_in[8];
    const float* W_g      = (const float*)d_in[9];
    // b_g (d_in[10]) == 0 and softmax-invariant anyway.

    char* ws = (char*)d_ws;
    size_t off = 0;
    unsigned short* wbf = (unsigned short*)(ws + off); off += (size_t)ATT_DIM * EPROJS * 2;
    float* e_buf  = (float*)(ws + off); off += (size_t)B_SZ * T_SZ * 4;
    float* dfb    = (float*)(ws + off); off += (size_t)B_SZ * ATT_DIM * 4;
    float* att_cv = (float*)(ws + off); off += (size_t)B_SZ * NCH * T_SZ * 4;
    float* w_ws   = (float*)(ws + off); off += (size_t)B_SZ * T_SZ * 4;
    float* part   = (float*)(ws + off); off += (size_t)B_SZ * 32 * EPROJS * 4;

    float* c_out = (float*)d_out;                    // [64][512]
    float* w_out = (float*)d_out + B_SZ * EPROJS;    // [64][2048]

    cvt_wenc<<<dim3(160), dim3(256), 0, stream>>>(W_enc, wbf);
    dec_feat_k<<<dim3(B_SZ), dim3(ATT_DIM), 0, stream>>>(dec_z, W_dec, b_enc, dfb);
    conv_k<<<dim3(B_SZ, NCH), dim3(256), 0, stream>>>(att_prev, conv_w, att_cv);
    energy_k<<<dim3(B_SZ * 32), dim3(256), 0, stream>>>(enc, wbf, dfb, att_cv, W_att, W_g, e_buf);
    softmax_k<<<dim3(B_SZ), dim3(256), 0, stream>>>(e_buf, len, w_out, w_ws);
    ctx_partial_k<<<dim3(B_SZ, 16), dim3(256), 0, stream>>>(enc, w_ws, part);
    ctx_reduce_k<<<dim3(B_SZ), dim3(128), 0, stream>>>(part, c_out);
}

// Round 6
// 250.586 us; speedup vs baseline: 2.1752x; 2.1752x over previous
//
#include <hip/hip_runtime.h>
#include <hip/hip_bf16.h>

#define B_SZ 64
#define T_SZ 2048
#define EPROJS 512
#define DUNITS 1024
#define ATT_DIM 320
#define NCH 10
#define KFILT 201
#define PAD 100

typedef __attribute__((ext_vector_type(8))) __bf16 bf16x8;
typedef __attribute__((ext_vector_type(4))) float f32x4;
typedef __attribute__((ext_vector_type(8))) unsigned short u16x8;

__device__ __forceinline__ unsigned short f2b(float f) {
    __bf16 h = (__bf16)f;
    return __builtin_bit_cast(unsigned short, h);
}

// ---------- W_enc f32 -> bf16 ----------
__global__ void cvt_wenc(const float* __restrict__ W, unsigned short* __restrict__ out) {
    int i = (blockIdx.x * 256 + threadIdx.x) * 4;
    float4 v = *(const float4*)(W + i);
    ushort4 o;
    o.x = f2b(v.x); o.y = f2b(v.y); o.z = f2b(v.z); o.w = f2b(v.w);
    *(ushort4*)(out + i) = o;
}

// ---------- dec_feat[b][a] = dec_z[b] . W_dec[a] + b_enc[a] ----------
__global__ void dec_feat_k(const float* __restrict__ dec_z, const float* __restrict__ W_dec,
                           const float* __restrict__ b_enc, float* __restrict__ df) {
    int b = blockIdx.x;
    int a = threadIdx.x;          // 320 threads
    const float4* z = (const float4*)(dec_z + b * DUNITS);
    const float4* w = (const float4*)(W_dec + (size_t)a * DUNITS);
    float s = b_enc[a];
    #pragma unroll 4
    for (int d = 0; d < DUNITS / 4; ++d) {
        float4 zv = z[d], wv = w[d];
        s += zv.x * wv.x + zv.y * wv.y + zv.z * wv.z + zv.w * wv.w;
    }
    df[b * ATT_DIM + a] = s;
}

// ---------- att_conv[b][c][t] ----------
__global__ void conv_k(const float* __restrict__ ap, const float* __restrict__ cw,
                       float* __restrict__ out) {
    int b = blockIdx.x, c = blockIdx.y;
    __shared__ float s_ap[T_SZ];
    __shared__ float s_cw[KFILT];
    int tid = threadIdx.x;
    for (int i = tid; i < T_SZ; i += 256) s_ap[i] = ap[b * T_SZ + i];
    for (int i = tid; i < KFILT; i += 256) s_cw[i] = cw[c * KFILT + i];
    __syncthreads();
    for (int j = 0; j < T_SZ / 256; ++j) {
        int t = tid + j * 256;
        int klo = max(0, PAD - t);
        int khi = min(KFILT, T_SZ + PAD - t);
        float s = 0.f;
        for (int k = klo; k < khi; ++k) s += s_ap[t - PAD + k] * s_cw[k];
        out[((size_t)(b * NCH + c)) * T_SZ + t] = s;
    }
}

// ---------- energy kernel: round-1 mechanics, BM=128 via 8 waves ----------
// All epilogue operands (W_att, df, W_g, conv) staged in LDS once — the global-load
// epilogue variants (r2-r5) made the compiler spill acc (512B/thread scratch traffic).
__global__ __launch_bounds__(512, 1) void energy_k(
    const float* __restrict__ enc, const unsigned short* __restrict__ wbf,
    const float* __restrict__ df, const float* __restrict__ att_conv,
    const float* __restrict__ W_att, const float* __restrict__ W_g,
    float* __restrict__ e_out)
{
    __shared__ unsigned short sW[ATT_DIM * 64];   // 40 KB, XOR-swizzled rows
    __shared__ float sDf[ATT_DIM], sWg[ATT_DIM], sWatt[ATT_DIM * NCH], sConv[NCH * 128];
    // total LDS ~60.4 KB -> 2 blocks/CU = 16 waves/CU

    int tid = threadIdx.x;
    int lane = tid & 63, wave = tid >> 6;         // 8 waves
    int blk = blockIdx.x;
    int b = blk >> 4;                             // 16 tiles of 128 t's per b
    int t0 = (blk & 15) << 7;

    for (int i = tid; i < ATT_DIM; i += 512) { sDf[i] = df[b * ATT_DIM + i]; sWg[i] = W_g[i]; }
    for (int i = tid; i < ATT_DIM * NCH; i += 512) sWatt[i] = W_att[i];
    for (int i = tid; i < NCH * 128; i += 512)
        sConv[i] = att_conv[((size_t)(b * NCH + (i >> 7))) * T_SZ + t0 + (i & 127)];

    f32x4 acc[20];
    #pragma unroll
    for (int n = 0; n < 20; ++n) acc[n] = (f32x4){0.f, 0.f, 0.f, 0.f};

    int m15 = lane & 15, kg = lane >> 4;
    int row = t0 + wave * 16 + m15;
    const float* aP = enc + ((size_t)b * T_SZ + row) * EPROJS;

    for (int k0 = 0; k0 < EPROJS; k0 += 64) {
        __syncthreads();
        // stage W tile [320][64] bf16, per-row XOR swizzle (r1-proven, 0 conflicts)
        #pragma unroll
        for (int r = 0; r < 5; ++r) {
            int idx = r * 512 + tid;          // 2560 chunks of 8 bf16
            int wr = idx >> 3, k8 = idx & 7;
            u16x8 v = *(const u16x8*)(wbf + (size_t)wr * EPROJS + k0 + k8 * 8);
            int k8s = k8 ^ (wr & 7);
            *(u16x8*)(sW + wr * 64 + k8s * 8) = v;
        }
        __syncthreads();
        #pragma unroll
        for (int kk = 0; kk < 2; ++kk) {
            const float4 a0 = *(const float4*)(aP + k0 + kk * 32 + kg * 8);
            const float4 a1 = *(const float4*)(aP + k0 + kk * 32 + kg * 8 + 4);
            bf16x8 af;
            af[0] = (__bf16)a0.x; af[1] = (__bf16)a0.y; af[2] = (__bf16)a0.z; af[3] = (__bf16)a0.w;
            af[4] = (__bf16)a1.x; af[5] = (__bf16)a1.y; af[6] = (__bf16)a1.z; af[7] = (__bf16)a1.w;
            int k8r = kk * 4 + kg;
            #pragma unroll
            for (int nt = 0; nt < 20; ++nt) {
                int wr = nt * 16 + m15;
                bf16x8 wf = *(const bf16x8*)(sW + wr * 64 + ((k8r ^ (wr & 7)) * 8));
                acc[nt] = __builtin_amdgcn_mfma_f32_16x16x32_bf16(af, wf, acc[nt], 0, 0, 0);
            }
        }
    }

    // epilogue: e[t] = sum_a Wg[a] * tanh(acc + df[a] + att_feat[t,a]) — all LDS operands
    int tl_base = wave * 16 + kg * 4;
    #pragma unroll
    for (int r = 0; r < 4; ++r) {
        int tl = tl_base + r;
        float s = 0.f;
        #pragma unroll
        for (int nt = 0; nt < 20; ++nt) {
            int col = nt * 16 + m15;
            float v = acc[nt][r] + sDf[col];
            float afeat = 0.f;
            #pragma unroll
            for (int c = 0; c < NCH; ++c) afeat += sWatt[col * NCH + c] * sConv[c * 128 + tl];
            v += afeat;
            v = fminf(fmaxf(v, -15.f), 15.f);
            float e2 = __expf(2.f * v);
            s += sWg[col] * ((e2 - 1.f) / (e2 + 1.f));
        }
        s += __shfl_xor(s, 1); s += __shfl_xor(s, 2);
        s += __shfl_xor(s, 4); s += __shfl_xor(s, 8);
        if (m15 == 0) e_out[b * T_SZ + t0 + tl] = s;
    }
}

// ---------- masked softmax over T, per b ----------
__global__ void softmax_k(const float* __restrict__ e, const int* __restrict__ len,
                          float* __restrict__ w_out, float* __restrict__ w_ws) {
    int b = blockIdx.x, tid = threadIdx.x;
    int lane = tid & 63, wave = tid >> 6;
    int L = len[b];
    float ev[8];
    float m = -1e30f;
    #pragma unroll
    for (int i = 0; i < 8; ++i) {
        int t = tid + i * 256;
        float x = e[b * T_SZ + t];
        if (t >= L) x = -1e30f;
        ev[i] = x;
        m = fmaxf(m, x);
    }
    #pragma unroll
    for (int o = 32; o > 0; o >>= 1) m = fmaxf(m, __shfl_xor(m, o));
    __shared__ float sred[4];
    if (lane == 0) sred[wave] = m;
    __syncthreads();
    m = fmaxf(fmaxf(sred[0], sred[1]), fmaxf(sred[2], sred[3]));

    float ex[8];
    float sum = 0.f;
    #pragma unroll
    for (int i = 0; i < 8; ++i) { ex[i] = __expf(2.f * (ev[i] - m)); sum += ex[i]; }
    #pragma unroll
    for (int o = 32; o > 0; o >>= 1) sum += __shfl_xor(sum, o);
    __shared__ float sred2[4];
    if (lane == 0) sred2[wave] = sum;
    __syncthreads();
    sum = sred2[0] + sred2[1] + sred2[2] + sred2[3];
    float inv = 1.f / sum;
    #pragma unroll
    for (int i = 0; i < 8; ++i) {
        int t = tid + i * 256;
        float w = ex[i] * inv;
        w_out[b * T_SZ + t] = w;
        w_ws[b * T_SZ + t] = w;
    }
}

// ---------- context partial: branchless, float4/lane ----------
__global__ void ctx_partial_k(const float* __restrict__ enc, const float* __restrict__ w,
                              float* __restrict__ part) {
    int b = blockIdx.x, tc = blockIdx.y, tid = threadIdx.x;
    int half = tid >> 7;          // 0/1: even/odd rows
    int c4 = tid & 127;           // float4 column index (128*4 = 512)
    f32x4 s = (f32x4){0.f, 0.f, 0.f, 0.f};
    int tb = tc * 128;
    #pragma unroll 4
    for (int i = half; i < 128; i += 2) {
        float wv = w[b * T_SZ + tb + i];              // masked rows have wv == 0 exactly
        f32x4 v = *(const f32x4*)(enc + ((size_t)b * T_SZ + tb + i) * EPROJS + c4 * 4);
        s += wv * v;
    }
    *(f32x4*)(part + ((size_t)(b * 32 + tc * 2 + half)) * EPROJS + c4 * 4) = s;
}

__global__ void ctx_reduce_k(const float* __restrict__ part, float* __restrict__ c_out) {
    int b = blockIdx.x;
    int c4 = threadIdx.x;         // 128 threads, float4 each
    f32x4 s = (f32x4){0.f, 0.f, 0.f, 0.f};
    #pragma unroll
    for (int tc = 0; tc < 32; ++tc)
        s += *(const f32x4*)(part + ((size_t)(b * 32 + tc)) * EPROJS + c4 * 4);
    *(f32x4*)(c_out + b * EPROJS + c4 * 4) = s;
}

extern "C" void kernel_launch(void* const* d_in, const int* in_sizes, int n_in,
                              void* d_out, int out_size, void* d_ws, size_t ws_size,
                              hipStream_t stream) {
    const float* enc      = (const float*)d_in[0];
    const int*   len      = (const int*)d_in[1];
    const float* dec_z    = (const float*)d_in[2];
    const float* att_prev = (const float*)d_in[3];
    const float* W_enc    = (const float*)d_in[4];
    const float* b_enc    = (const float*)d_in[5];
    const float* W_dec    = (const float*)d_in[6];
    const float* W_att    = (const float*)d_in[7];
    const float* conv_w   = (const float*)d_in[8];
    const float* W_g      = (const float*)d_in[9];
    // b_g (d_in[10]) == 0 and softmax-invariant anyway.

    char* ws = (char*)d_ws;
    size_t off = 0;
    unsigned short* wbf = (unsigned short*)(ws + off); off += (size_t)ATT_DIM * EPROJS * 2;
    float* e_buf  = (float*)(ws + off); off += (size_t)B_SZ * T_SZ * 4;
    float* dfb    = (float*)(ws + off); off += (size_t)B_SZ * ATT_DIM * 4;
    float* att_cv = (float*)(ws + off); off += (size_t)B_SZ * NCH * T_SZ * 4;
    float* w_ws   = (float*)(ws + off); off += (size_t)B_SZ * T_SZ * 4;
    float* part   = (float*)(ws + off); off += (size_t)B_SZ * 32 * EPROJS * 4;

    float* c_out = (float*)d_out;                    // [64][512]
    float* w_out = (float*)d_out + B_SZ * EPROJS;    // [64][2048]

    cvt_wenc<<<dim3(160), dim3(256), 0, stream>>>(W_enc, wbf);
    dec_feat_k<<<dim3(B_SZ), dim3(ATT_DIM), 0, stream>>>(dec_z, W_dec, b_enc, dfb);
    conv_k<<<dim3(B_SZ, NCH), dim3(256), 0, stream>>>(att_prev, conv_w, att_cv);
    energy_k<<<dim3(B_SZ * 16), dim3(512), 0, stream>>>(enc, wbf, dfb, att_cv, W_att, W_g, e_buf);
    softmax_k<<<dim3(B_SZ), dim3(256), 0, stream>>>(e_buf, len, w_out, w_ws);
    ctx_partial_k<<<dim3(B_SZ, 16), dim3(256), 0, stream>>>(enc, w_ws, part);
    ctx_reduce_k<<<dim3(B_SZ), dim3(128), 0, stream>>>(part, c_out);
}